// Round 4
// baseline (18523.833 us; speedup 1.0000x reference)
//
#include <hip/hip_runtime.h>
#include <hip/hip_bf16.h>
#include <math.h>

// ---------------- problem constants ----------------
#define BB   8
#define CH   32
#define TT   504
#define FFp  168      // padded F
#define OF   161      // original F
#define KSZ  8
#define HID  256
#define NG   1024     // 4*H
#define NHh  4
#define EE   4
#define CVv  8
#define N1   4032     // B*T  (intra seqs)
#define N2   1344     // B*Fp (inter seqs)
#define LFi  21       // F/KS
#define LTi  63       // T/KS
#define EPSf 1e-5f

#define AS1 __attribute__((address_space(1)))
#define AS3 __attribute__((address_space(3)))

typedef __hip_bfloat16 bf16;
typedef __attribute__((ext_vector_type(8))) short s16x8;
typedef __attribute__((ext_vector_type(4))) float f32x4;

__device__ __forceinline__ float b2f(bf16 v) { return __bfloat162float(v); }
__device__ __forceinline__ bf16 f2b(float v) { return __float2bfloat16(v); }
__device__ __forceinline__ float us2f(unsigned short u) {
  return __uint_as_float(((unsigned)u) << 16);
}
__device__ __forceinline__ unsigned short f2bu(float v) {   // RNE bf16 bits
  unsigned u = __float_as_uint(v);
  unsigned r = u + 0x7fffu + ((u >> 16) & 1u);
  return (unsigned short)(r >> 16);
}

__device__ __forceinline__ float sigm(float x) { return 1.f / (1.f + __expf(-x)); }
__device__ __forceinline__ float tanh_f(float x) {
  x = fminf(15.f, fmaxf(-15.f, x));
  float e = __expf(2.f * x);
  return (e - 1.f) / (e + 1.f);
}

// block = 256 threads (4 waves). red must be float[8] shared.
__device__ __forceinline__ void block_reduce2(float& s1, float& s2, float* red) {
#pragma unroll
  for (int off = 32; off > 0; off >>= 1) {
    s1 += __shfl_down(s1, off, 64);
    s2 += __shfl_down(s2, off, 64);
  }
  int lane = threadIdx.x & 63, wv = threadIdx.x >> 6;
  __syncthreads();
  if (lane == 0) { red[wv * 2] = s1; red[wv * 2 + 1] = s2; }
  __syncthreads();
  s1 = red[0] + red[2] + red[4] + red[6];
  s2 = red[1] + red[3] + red[5] + red[7];
}

// ---------------- K1: input conv 2->32, 3x3, pad 1 (LDS-tiled) ----------------
__global__ __launch_bounds__(192) void conv_in_k(const float* __restrict__ x,
                                                 const float* __restrict__ w,
                                                 const float* __restrict__ bias,
                                                 bf16* __restrict__ out) {
  __shared__ float xs[2 * 3 * (OF + 3)];
  int bt = blockIdx.x;
  int b = bt / TT, t = bt % TT;
  int tid = threadIdx.x;
  for (int i = tid; i < 2 * 3 * (OF + 3); i += 192) {
    int ci = i / (3 * (OF + 3));
    int rem = i % (3 * (OF + 3));
    int rr = rem / (OF + 3);
    int f = rem % (OF + 3);
    int ts = t + rr - 1;
    float v = 0.f;
    if (ts >= 0 && ts < TT && f < OF) v = x[((size_t)(b * 2 + ci) * TT + ts) * OF + f];
    xs[i] = v;
  }
  __syncthreads();
  int f = tid;
  if (f < OF) {
    float xv[2][3][3];
#pragma unroll
    for (int ci = 0; ci < 2; ci++)
#pragma unroll
      for (int kh = 0; kh < 3; kh++)
#pragma unroll
        for (int kw = 0; kw < 3; kw++) {
          int ff = f + kw - 1;
          xv[ci][kh][kw] = (ff < 0) ? 0.f : xs[(ci * 3 + kh) * (OF + 3) + ff];
        }
    for (int co = 0; co < CH; co++) {
      float acc = bias[co];
#pragma unroll
      for (int ci = 0; ci < 2; ci++)
#pragma unroll
        for (int kh = 0; kh < 3; kh++)
#pragma unroll
          for (int kw = 0; kw < 3; kw++)
            acc += xv[ci][kh][kw] * w[((co * 2 + ci) * 3 + kh) * 3 + kw];
      out[((size_t)(b * CH + co) * TT + t) * OF + f] = f2b(acc);
    }
  }
}

// ---------------- K2/K3: global per-batch norm ----------------
__global__ __launch_bounds__(256) void gn_reduce_k(const bf16* __restrict__ xin,
                                                   float* __restrict__ stats) {
  const int M = CH * TT * OF;   // 2,596,608
  int b = blockIdx.x >> 6;
  int part = blockIdx.x & 63;
  const bf16* p = xin + (size_t)b * M;
  float s1 = 0.f, s2 = 0.f;
  for (int i = part * 256 + threadIdx.x; i < M; i += 64 * 256) {
    float v = b2f(p[i]);
    s1 += v; s2 += v * v;
  }
  __shared__ float red[8];
  block_reduce2(s1, s2, red);
  if (threadIdx.x == 0) {
    atomicAdd(&stats[b * 2], s1);
    atomicAdd(&stats[b * 2 + 1], s2);
  }
}

__global__ __launch_bounds__(256) void gn_apply_k(const bf16* __restrict__ xin,
                                                  const float* __restrict__ stats,
                                                  const float* __restrict__ g,
                                                  const float* __restrict__ bb,
                                                  bf16* __restrict__ act) {
  int gid = blockIdx.x * 256 + threadIdx.x;       // B*CH*TT*FFp = 21,676,032 exact
  int f = gid % FFp;
  int t = (gid / FFp) % TT;
  int c = (gid / (FFp * TT)) % CH;
  int b = gid / (FFp * TT * CH);
  float v = 0.f;
  if (f < OF) {
    const float M = (float)(CH * TT * OF);
    float mu = stats[b * 2] / M;
    float var = stats[b * 2 + 1] / M - mu * mu;
    float xv = b2f(xin[((size_t)(b * CH + c) * TT + t) * OF + f]);
    v = (xv - mu) * rsqrtf(var + EPSf) * g[c] + bb[c];   // NOTE: no outer +eps here
  }
  act[gid] = f2b(v);
}

// ---------------- K4a: intra ln + unfold, coalesced 16-B record writes ----------------
__global__ __launch_bounds__(256) void ln_unfold_k(const bf16* __restrict__ xin,
                                                   const float* __restrict__ g,
                                                   const float* __restrict__ bb,
                                                   bf16* __restrict__ out) {
  __shared__ float sm[CH * FFp];
  __shared__ float mu_s[FFp], rs_s[FFp];
  __shared__ float gg[CH], bv[CH];
  int bt = blockIdx.x;
  int b = bt / TT, t = bt % TT;
  int tid = threadIdx.x;
  if (tid < CH) { gg[tid] = g[tid]; bv[tid] = bb[tid]; }
  const bf16* base = xin + ((size_t)b * CH * TT + t) * FFp;
  for (int idx = tid; idx < CH * FFp; idx += 256) {
    int c = idx / FFp, f = idx % FFp;
    sm[idx] = b2f(base[(size_t)c * TT * FFp + f]);
  }
  __syncthreads();
  if (tid < FFp) {
    int f = tid;
    float s1 = 0.f, s2 = 0.f;
#pragma unroll
    for (int c = 0; c < CH; c++) { float v = sm[c * FFp + f]; s1 += v; s2 += v * v; }
    float mu = s1 / CH;
    float var = s2 / CH - mu * mu;
    mu_s[f] = mu;
    rs_s[f] = 1.f / (sqrtf(var + EPSf) + EPSf);
  }
  __syncthreads();
  unsigned short* outu = (unsigned short*)out;
  for (int ch = tid; ch < LFi * CH; ch += 256) {     // 672 records
    int gI = ch >> 5, c = ch & 31;
    float gc = gg[c], bc = bv[c];
    unsigned short o8[8];
#pragma unroll
    for (int k = 0; k < 8; k++) {
      int f = gI * 8 + k;
      float v = (sm[c * FFp + f] - mu_s[f]) * rs_s[f] * gc + bc;
      o8[k] = f2bu(v);
    }
    *(uint4*)(outu + ((size_t)gI * N1 + bt) * 256 + c * 8) = *(uint4*)o8;
  }
}

// ---------------- K4b: inter ln + unfold, 8-t blocks, coalesced writes ----------------
__global__ __launch_bounds__(256) void ln_unfold8_k(const bf16* __restrict__ xin,
                                                    const float* __restrict__ g,
                                                    const float* __restrict__ bb,
                                                    bf16* __restrict__ out) {
  __shared__ short smb[8 * CH * FFp];              // 86016 B, [t8*32+c][f]
  __shared__ float mu_s[8 * FFp], rs_s[8 * FFp];   // 10752 B
  __shared__ float gg[CH], bv[CH];
  int tg = blockIdx.x, b = blockIdx.y;
  int tid = threadIdx.x;
  if (tid < CH) { gg[tid] = g[tid]; bv[tid] = bb[tid]; }
  const short* src = (const short*)xin;
  for (int idx = tid; idx < 8 * CH * (FFp / 8); idx += 256) {   // 5376 chunks of 8
    int t8 = idx / (CH * 21);
    int rem = idx % (CH * 21);
    int c = rem / 21, fc = rem % 21;
    s16x8 v = *(const s16x8*)(src + ((size_t)(b * CH + c) * TT + tg * 8 + t8) * FFp + fc * 8);
    *(s16x8*)(&smb[(t8 * CH + c) * FFp + fc * 8]) = v;
  }
  __syncthreads();
  for (int p = tid; p < 8 * FFp; p += 256) {       // 1344 (t8,f) pairs
    int t8 = p / FFp, f = p % FFp;
    float s1 = 0.f, s2 = 0.f;
#pragma unroll
    for (int c = 0; c < CH; c++) {
      float v = us2f((unsigned short)smb[(t8 * CH + c) * FFp + f]);
      s1 += v; s2 += v * v;
    }
    float mu = s1 / CH;
    float var = s2 / CH - mu * mu;
    mu_s[p] = mu;
    rs_s[p] = 1.f / (sqrtf(var + EPSf) + EPSf);
  }
  __syncthreads();
  unsigned short* outu = (unsigned short*)out;
  for (int ch = tid; ch < FFp * CH; ch += 256) {   // 5376 records
    int f = ch >> 5, c = ch & 31;
    float gc = gg[c], bc = bv[c];
    unsigned short o8[8];
#pragma unroll
    for (int k = 0; k < 8; k++) {
      float v = us2f((unsigned short)smb[(k * CH + c) * FFp + f]);
      v = (v - mu_s[k * FFp + f]) * rs_s[k * FFp + f] * gc + bc;
      o8[k] = f2bu(v);
    }
    *(uint4*)(outu + ((size_t)tg * N2 + b * FFp + f) * 256 + c * 8) = *(uint4*)o8;
  }
}

// ---------------- K5a: weight prep — reorder W=[wih|whh] into B-fragment blob ---------
// blob[nt(64)][ks(16)][lane(64)][j(8)], value = Wcat[n][k]:
//   n = nt*16 + (lane&15), k = ks*32 + (lane>>4)*8 + j
//   Wcat[n][k] = k<256 ? wih[n][k] : whh[n][k-256]
__global__ __launch_bounds__(256) void lstm_prep_k(const float* __restrict__ wih0,
                                                   const float* __restrict__ whh0,
                                                   bf16* __restrict__ blob0) {
  int dir = blockIdx.y;
  const float* wih = wih0 + (size_t)dir * 262144;
  const float* whh = whh0 + (size_t)dir * 262144;
  unsigned short* blob = (unsigned short*)(blob0 + (size_t)dir * 524288);
  int gid = blockIdx.x * 256 + threadIdx.x;     // 0..65535
  int lane = gid & 63;
  int ks = (gid >> 6) & 15;
  int nt = gid >> 10;
  int n = nt * 16 + (lane & 15);
  int kb = ks * 32 + (lane >> 4) * 8;
  unsigned short o8[8];
#pragma unroll
  for (int j = 0; j < 8; j++) {
    int k = kb + j;
    float v = (k < 256) ? wih[n * 256 + k] : whh[n * 256 + (k - 256)];
    o8[j] = f2bu(v);
  }
  *(uint4*)(blob + (size_t)gid * 8) = *(uint4*)o8;
}

// ---------------- K5b: MFMA LSTM, M=32/block, REGISTER-staged B-stream ----------------
// R13: R2/R3 falsified aggregate-BW and requester-count theories (halving blocks and
// 4-way de-phasing left per-block time ~unchanged). Surviving theory: per-CU cap on
// the global_load_lds path itself (~13 GB/s/CU delivered, invariant across configs).
// Structural fix: B-fragments are WAVE-PRIVATE (bst_w was a per-wave LDS slice that
// only its own wave ever read) -> LDS staging for B is pure overhead. Load B straight
// into VGPRs via normal global loads (deep VMEM queues, ~150 GB/s/CU L2 link) and
// feed MFMA directly. Correctness of B consumption is now enforced by the COMPILER's
// register-dependency waitcnts — the R1-class hand-rolled wait races are structurally
// impossible for the B-stream. Depth-4 register pipeline bbuf[4][2] (all indices
// compile-time: rule-#20 safe); explicit vmcnt ladder kept as scheduling intent:
// steady vmcnt(6), tail 4/2/0 at C=61/62/63 (issue-ahead 4, 2 loads/chunk).
// x/h staging stays in LDS (genuinely wave-shared), drained by BARRIER-A as before.
// LDS drops 128 KiB -> 32 KiB. PH rotation kept from R3 (unchanged variable).
template<int PH>
__device__ __forceinline__ void lstm_run(short* __restrict__ afr,
                                         const short* __restrict__ xzs,
                                         const short* __restrict__ blob,
                                         const float* __restrict__ bih,
                                         const float* __restrict__ bhh,
                                         unsigned short* __restrict__ houtu,
                                         int N, int Ls, int hstride, int hoff,
                                         int n0, int dirrev, int w, int lane) {
  int tid = w * 64 + lane;
  int l15 = lane & 15, lq = lane >> 4;

  float bias[4][2];
#pragma unroll
  for (int q = 0; q < 4; q++)
#pragma unroll
    for (int j = 0; j < 2; j++) {
      int n = q * 256 + (2 * w + j) * 16 + l15;
      bias[q][j] = bih[n] + bhh[n];
    }
  for (int i = tid; i < 8192; i += 512) afr[8192 + i] = 0;   // h frags = 0
  float cst[16];
#pragma unroll
  for (int i = 0; i < 16; i++) cst[i] = 0.f;

  s16x8 bbuf[4][2];   // rotating register pipeline, static indices only

// position P in [0,64): s=P>>1, h2=P&1; rotated quad a=((s>>3)+PH)&3 (compile-time),
// r=s&7 -> nt=(r>>1)*16+2w+(r&1); frags kf = a*4 + h2*2 + {0,1}. Slot P&3.
#define BQ_ISSUE(P)                                                              \
  {                                                                              \
    const int a_ = (((P) >> 4) + PH) & 3;                                        \
    const int r_ = ((P) >> 1) & 7, h2_ = (P) & 1;                                \
    const int nt_ = (r_ >> 1) * 16 + 2 * w + (r_ & 1);                           \
    const short* gb_ = blob + (size_t)nt_ * 8192 + (a_ * 4 + h2_ * 2) * 512 + lane * 8; \
    bbuf[(P) & 3][0] = *(const s16x8*)(gb_);                                     \
    bbuf[(P) & 3][1] = *(const s16x8*)(gb_ + 512);                               \
  }

  for (int st = 0; st < Ls; st++) {
    int t = dirrev ? (Ls - 1 - st) : st;
    // stage x_t via DMA (wave-shared; non-temporal read-once stream)
    {
      const short* gx = xzs + ((size_t)t * N + n0 + l15) * 256 + (w * 4 + lq) * 8;
      __builtin_amdgcn_global_load_lds((const AS1 void*)gx,
                                       (AS3 void*)(afr + (w * 2 + 0) * 512), 16, 0, 2);
      __builtin_amdgcn_global_load_lds((const AS1 void*)(gx + 16 * 256),
                                       (AS3 void*)(afr + (w * 2 + 1) * 512), 16, 0, 2);
    }
    BQ_ISSUE(0);
    BQ_ISSUE(1);
    BQ_ISSUE(2);
    BQ_ISSUE(3);
    __syncthreads();   // BARRIER-A: drains x DMA, h visible (also drains B prologue)

    f32x4 acc[2][4][2];
#pragma unroll
    for (int mt = 0; mt < 2; mt++)
#pragma unroll
      for (int q = 0; q < 4; q++)
#pragma unroll
        for (int j = 0; j < 2; j++)
          acc[mt][q][j] = (f32x4){bias[q][j], bias[q][j], bias[q][j], bias[q][j]};

    s16x8 af[4][2];
#pragma unroll
    for (int C = 0; C < 64; C++) {
      const int s = C >> 1, h2 = C & 1;
      const int rR = s & 7;
      const int q = rR >> 1, j = rR & 1;     // static acc index
      if (rR == 0 && h2 == 0) {
        const int a = ((s >> 3) + PH) & 3;   // compile-time under template
#pragma unroll
        for (int k = 0; k < 4; k++)
#pragma unroll
          for (int mt = 0; mt < 2; mt++)
            af[k][mt] = *(const s16x8*)(&afr[(((a * 4 + k) * 2 + mt) * 64 + lane) * 8]);
      }
      // advisory pipeline waits (compiler's register-dep waits guarantee correctness):
      // outstanding chunks at C: [C, min(C+3,63)] -> allow 2*(chunks after C) loads.
      if (C <= 60)      __builtin_amdgcn_s_waitcnt(0x0F76);   // vmcnt(6)
      else if (C == 61) __builtin_amdgcn_s_waitcnt(0x0F74);   // vmcnt(4)
      else if (C == 62) __builtin_amdgcn_s_waitcnt(0x0F72);   // vmcnt(2)
      else              __builtin_amdgcn_s_waitcnt(0x0F70);   // vmcnt(0)
#pragma unroll
      for (int k = 0; k < 2; k++) {
        s16x8 bf = bbuf[C & 3][k];
        acc[0][q][j] = __builtin_amdgcn_mfma_f32_16x16x32_bf16(af[h2 * 2 + k][0], bf, acc[0][q][j], 0, 0, 0);
        acc[1][q][j] = __builtin_amdgcn_mfma_f32_16x16x32_bf16(af[h2 * 2 + k][1], bf, acc[1][q][j], 0, 0, 0);
      }
      if (C < 60) BQ_ISSUE(C + 4);
    }
    __syncthreads();   // BARRIER-B: all afr reads done before h overwrite

    // epilogue: gates -> (h, c); h to global + h-frag LDS
#pragma unroll
    for (int mt = 0; mt < 2; mt++)
#pragma unroll
      for (int j = 0; j < 2; j++) {
        int d = (2 * w + j) * 16 + l15;
        int slotb = ((8 + (d >> 5)) * 2 + mt) * 64 + ((d >> 3) & 3) * 16;
#pragma unroll
        for (int r = 0; r < 4; r++) {
          int m = lq * 4 + r;
          float iv = sigm(acc[mt][0][j][r]);
          float fv = sigm(acc[mt][1][j][r]);
          float gv = tanh_f(acc[mt][2][j][r]);
          float ov = sigm(acc[mt][3][j][r]);
          float c = fv * cst[mt * 8 + j * 4 + r] + iv * gv;
          cst[mt * 8 + j * 4 + r] = c;
          float h = ov * tanh_f(c);
          unsigned short hb = f2bu(h);
          houtu[((size_t)t * N + n0 + mt * 16 + m) * hstride + hoff + d] = hb;
          afr[(slotb + m) * 8 + (d & 7)] = (short)hb;
        }
      }
  }
#undef BQ_ISSUE
}

__global__ __launch_bounds__(512) void lstm_mfma_k(const bf16* __restrict__ xz,
                                                   const bf16* __restrict__ blob0,
                                                   const float* __restrict__ bih0,
                                                   const float* __restrict__ bhh0,
                                                   bf16* __restrict__ hout,
                                                   int N, int Ls, int hstride, int bidir) {
  // afr: 32 KiB, slot = (kf*2 + mt)*64 + kg*16 + m15, kf<8 = x (k 0..255), kf>=8 = h
  __shared__ __attribute__((aligned(16))) short afr[16 * 2 * 64 * 8];
  int tid = threadIdx.x;
  int w = tid >> 6, lane = tid & 63;
  int dir = blockIdx.y;
  const short* blob = (const short*)(blob0 + (size_t)dir * 524288);
  const float* bih = bih0 + dir * NG;
  const float* bhh = bhh0 + dir * NG;
  int hoff = dir * 256;
  int n0 = blockIdx.x * 32;
  int dirrev = (bidir && dir) ? 1 : 0;
  unsigned short* houtu = (unsigned short*)hout;
  const short* xzs = (const short*)xz;
  int PH = ((blockIdx.x >> 3) + blockIdx.x) & 3;   // de-phase under RR or chunked XCD map
  switch (PH) {
    case 0: lstm_run<0>(afr, xzs, blob, bih, bhh, houtu, N, Ls, hstride, hoff, n0, dirrev, w, lane); break;
    case 1: lstm_run<1>(afr, xzs, blob, bih, bhh, houtu, N, Ls, hstride, hoff, n0, dirrev, w, lane); break;
    case 2: lstm_run<2>(afr, xzs, blob, bih, bhh, houtu, N, Ls, hstride, hoff, n0, dirrev, w, lane); break;
    default: lstm_run<3>(afr, xzs, blob, bih, bhh, houtu, N, Ls, hstride, hoff, n0, dirrev, w, lane); break;
  }
}

// ---------------- K6: fold GEMM (M=84672, N=256) + bias + residual, scatter epilogue ---
__global__ __launch_bounds__(256) void fold_gemm_k(const bf16* __restrict__ A,
                                                   const float* __restrict__ Bw,
                                                   const float* __restrict__ linb,
                                                   const bf16* __restrict__ resid,
                                                   bf16* __restrict__ outp,
                                                   int K, int mode) {
  __shared__ float As[16 * 68];
  __shared__ float Bs[16 * 64];
  int tid = threadIdx.x;
  int n0 = blockIdx.x * 64;
  int m0 = blockIdx.y * 64;
  int tr = tid >> 4, tc = tid & 15;
  float acc[4][4] = {};
  int arow = tid >> 2, akg = (tid & 3) * 4;
  int bkk = tid >> 4, bc4 = (tid & 15) * 4;
  for (int k0 = 0; k0 < K; k0 += 16) {
    ushort4 avu = *(const ushort4*)((const unsigned short*)A + (size_t)(m0 + arow) * K + k0 + akg);
    float4 bv = *(const float4*)(Bw + (size_t)(k0 + bkk) * 256 + n0 + bc4);
    __syncthreads();
    As[(akg + 0) * 68 + arow] = us2f(avu.x);
    As[(akg + 1) * 68 + arow] = us2f(avu.y);
    As[(akg + 2) * 68 + arow] = us2f(avu.z);
    As[(akg + 3) * 68 + arow] = us2f(avu.w);
    *(float4*)(&Bs[bkk * 64 + bc4]) = bv;
    __syncthreads();
#pragma unroll
    for (int kk = 0; kk < 16; kk++) {
      float4 a4 = *(const float4*)(&As[kk * 68 + tr * 4]);
      float4 b4 = *(const float4*)(&Bs[kk * 64 + tc * 4]);
      float aa[4] = {a4.x, a4.y, a4.z, a4.w};
      float bb_[4] = {b4.x, b4.y, b4.z, b4.w};
#pragma unroll
      for (int i = 0; i < 4; i++)
#pragma unroll
        for (int j = 0; j < 4; j++) acc[i][j] += aa[i] * bb_[j];
    }
  }
#pragma unroll
  for (int i = 0; i < 4; i++) {
    int r = m0 + tr * 4 + i;
#pragma unroll
    for (int j = 0; j < 4; j++) {
      int col = n0 + tc * 4 + j;
      int c = col >> 3, kp = col & 7;
      float v = acc[i][j] + linb[c];
      if (mode == 0) {
        int l = r / N1, n = r % N1;
        int b = n / TT, t = n % TT;
        size_t o = ((size_t)(b * CH + c) * TT + t) * FFp + (l * 8 + kp);
        outp[o] = f2b(v + b2f(resid[o]));
      } else {
        int l = r / N2, n = r % N2;
        int b = n / FFp, fq = n % FFp;
        int t = l * 8 + kp;
        if (fq < OF) {
          size_t o = ((size_t)(b * CH + c) * TT + t) * OF + fq;
          size_t ri = ((size_t)(b * CH + c) * TT + t) * FFp + fq;
          outp[o] = f2b(v + b2f(resid[ri]));
        }
      }
    }
  }
}

// ---------------- K8: fused QKV projection + prelu + ln_cf_head ----------------
__global__ __launch_bounds__(256) void qkv_k(const bf16* __restrict__ interc,
    const float* __restrict__ qw, const float* __restrict__ qb, const float* __restrict__ qa,
    const float* __restrict__ qg, const float* __restrict__ qbeta,
    const float* __restrict__ kw, const float* __restrict__ kb, const float* __restrict__ ka,
    const float* __restrict__ kg, const float* __restrict__ kbeta,
    const float* __restrict__ vw, const float* __restrict__ vb, const float* __restrict__ va,
    const float* __restrict__ vg, const float* __restrict__ vbeta,
    bf16* __restrict__ qo, bf16* __restrict__ ko, bf16* __restrict__ vo) {
  __shared__ float sm[CH * OF];     // 5152
  __shared__ float wb[16 * 32];
  __shared__ float wbias[16];
  __shared__ float yb[16 * OF];     // 2576: [0:4) Q-e, [4:8) K-e, [8:16) V-cv
  __shared__ float red[8];
  int bt = blockIdx.x, h = blockIdx.y;
  int b = bt / TT, t = bt % TT;
  int tid = threadIdx.x;
  const bf16* src = interc + ((size_t)b * CH * TT + t) * OF;
  for (int idx = tid; idx < CH * OF; idx += 256) {
    int c = idx / OF, f = idx % OF;
    sm[idx] = b2f(src[(size_t)c * TT * OF + f]);
  }
  for (int idx = tid; idx < 512; idx += 256) {
    int e = idx >> 5, c = idx & 31;
    float w;
    if (e < 4) w = qw[(h * 4 + e) * 32 + c];
    else if (e < 8) w = kw[(h * 4 + e - 4) * 32 + c];
    else w = vw[(h * 8 + e - 8) * 32 + c];
    wb[idx] = w;
  }
  if (tid < 16) {
    float bv;
    if (tid < 4) bv = qb[h * 4 + tid];
    else if (tid < 8) bv = kb[h * 4 + tid - 4];
    else bv = vb[h * 8 + tid - 8];
    wbias[tid] = bv;
  }
  __syncthreads();
  float aQ = qa[h], aK = ka[h], aV = va[h];
  for (int idx = tid; idx < 16 * OF; idx += 256) {
    int e = idx / OF, f = idx % OF;
    float accv = wbias[e];
#pragma unroll
    for (int c = 0; c < 32; c++) accv += sm[c * OF + f] * wb[e * 32 + c];
    float a = e < 4 ? aQ : (e < 8 ? aK : aV);
    yb[idx] = accv >= 0.f ? accv : a * accv;
  }
  __syncthreads();
  for (int seg = 0; seg < 3; seg++) {
    int s0 = (seg == 0) ? 0 : ((seg == 1) ? 644 : 1288);
    int len = (seg == 2) ? 1288 : 644;
    float s1 = 0.f, s2 = 0.f;
    for (int i = tid; i < len; i += 256) { float v = yb[s0 + i]; s1 += v; s2 += v * v; }
    block_reduce2(s1, s2, red);
    float mu = s1 / len;
    float var = s2 / len - mu * mu;
    float rs = 1.f / (sqrtf(var + EPSf) + EPSf);
    const float* gp; const float* bp; bf16* op; int nch;
    if (seg == 0) { gp = qg; bp = qbeta; op = qo; nch = 4; }
    else if (seg == 1) { gp = kg; bp = kbeta; op = ko; nch = 4; }
    else { gp = vg; bp = vbeta; op = vo; nch = 8; }
    for (int i = tid; i < len; i += 256) {
      int e = i / OF, f = i % OF;
      float v = (yb[s0 + i] - mu) * rs * gp[(h * nch + e) * OF + f] + bp[(h * nch + e) * OF + f];
      op[(((size_t)(h * BB + b) * nch + e) * TT + t) * OF + f] = f2b(v);
    }
  }
}

// ---------------- K9: banded causal attention (lookback 5) ----------------
__global__ __launch_bounds__(256) void attn_k(const bf16* __restrict__ Q,
                                              const bf16* __restrict__ Kt,
                                              const bf16* __restrict__ V,
                                              bf16* __restrict__ O) {
  int t = blockIdx.x;
  int hb = blockIdx.y;            // h*8 + b
  int h = hb >> 3, b = hb & 7;
  int tid = threadIdx.x;
  int nv = min(t, 5) + 1;
  const float scale = 0.0394055201f;   // 1/sqrt(644)
  __shared__ float redl[24];
  float part[6] = {0, 0, 0, 0, 0, 0};
  size_t qkbase = ((size_t)(h * BB + b) * EE) * TT * OF;
  for (int i = tid; i < EE * OF; i += 256) {
    int e = i / OF, f = i % OF;
    float qv = b2f(Q[qkbase + ((size_t)e * TT + t) * OF + f]);
#pragma unroll
    for (int d = 0; d < 6; d++)
      if (d < nv) part[d] += qv * b2f(Kt[qkbase + ((size_t)e * TT + (t - d)) * OF + f]);
  }
#pragma unroll
  for (int d = 0; d < 6; d++)
#pragma unroll
    for (int off = 32; off > 0; off >>= 1) part[d] += __shfl_down(part[d], off, 64);
  int lane = tid & 63, wv = tid >> 6;
  if (lane == 0) {
#pragma unroll
    for (int d = 0; d < 6; d++) redl[wv * 6 + d] = part[d];
  }
  __syncthreads();
  float a[6], sv[6];
  float m = -1e30f;
#pragma unroll
  for (int d = 0; d < 6; d++)
    if (d < nv) {
      float s = (redl[d] + redl[6 + d] + redl[12 + d] + redl[18 + d]) * scale;
      sv[d] = s;
      m = fmaxf(m, s);
    }
  float denom = 0.f;
#pragma unroll
  for (int d = 0; d < 6; d++)
    if (d < nv) { a[d] = __expf(sv[d] - m); denom += a[d]; }
  float inv = 1.f / denom;
  size_t vbase = ((size_t)(h * BB + b) * CVv) * TT * OF;
  for (int i = tid; i < CVv * OF; i += 256) {
    int cv = i / OF, f = i % OF;
    float o = 0.f;
#pragma unroll
    for (int d = 0; d < 6; d++)
      if (d < nv) o += a[d] * b2f(V[vbase + ((size_t)cv * TT + (t - d)) * OF + f]);
    O[(((size_t)b * CH + h * CVv + cv) * TT + t) * OF + f] = f2b(o * inv);
  }
}

// ---------------- K10: proj + prelu + ln_cf_proj + residual + re-pad ----------------
__global__ __launch_bounds__(256) void proj_k(const bf16* __restrict__ ob,
                                              const float* __restrict__ pw,
                                              const float* __restrict__ pb,
                                              const float* __restrict__ pa,
                                              const float* __restrict__ pg,
                                              const float* __restrict__ pbeta,
                                              const bf16* __restrict__ interc,
                                              bf16* __restrict__ act) {
  __shared__ float sm[CH * OF];
  __shared__ float wsm[CH * CH];
  __shared__ float yb[CH * OF];
  __shared__ float red[8];
  int bt = blockIdx.x;
  int b = bt / TT, t = bt % TT;
  int tid = threadIdx.x;
  const bf16* src = ob + ((size_t)b * CH * TT + t) * OF;
  for (int idx = tid; idx < CH * OF; idx += 256) {
    int c = idx / OF, f = idx % OF;
    sm[idx] = b2f(src[(size_t)c * TT * OF + f]);
  }
  for (int idx = tid; idx < CH * CH; idx += 256) wsm[idx] = pw[idx];
  __syncthreads();
  float aP = pa[0];
  for (int idx = tid; idx < CH * OF; idx += 256) {
    int d = idx / OF, f = idx % OF;
    float accv = pb[d];
#pragma unroll
    for (int c = 0; c < 32; c++) accv += sm[c * OF + f] * wsm[d * 32 + c];
    yb[idx] = accv >= 0.f ? accv : aP * accv;
  }
  __syncthreads();
  float s1 = 0.f, s2 = 0.f;
  for (int i = tid; i < CH * OF; i += 256) { float v = yb[i]; s1 += v; s2 += v * v; }
  block_reduce2(s1, s2, red);
  const float Mn = (float)(CH * OF);
  float mu = s1 / Mn;
  float var = s2 / Mn - mu * mu;
  float rs = 1.f / (sqrtf(var + EPSf) + EPSf);
  for (int idx = tid; idx < CH * FFp; idx += 256) {
    int d = idx / FFp, f = idx % FFp;
    float v = 0.f;
    if (f < OF) {
      float y = (yb[d * OF + f] - mu) * rs * pg[d * OF + f] + pbeta[d * OF + f];
      v = y + b2f(interc[((size_t)(b * CH + d) * TT + t) * OF + f]);
    }
    act[((size_t)(b * CH + d) * TT + t) * FFp + f] = f2b(v);
  }
}

// ---------------- K11: output deconv (LDS-tiled 3x3 conv over 32ch) -------------------
// NOTE: grid MUST be exactly B*TT = 4032 (block-per-(b,t)); larger grids write OOB.
__global__ __launch_bounds__(256) void deconv_k(const bf16* __restrict__ act,
                                                const float* __restrict__ w,
                                                const float* __restrict__ bias,
                                                float* __restrict__ out) {
  __shared__ float ash[CH * 3 * FFp];   // 64512 B
  int bt = blockIdx.x;
  int b = bt / TT, t = bt % TT;
  int tid = threadIdx.x;
  const short* acts = (const short*)act;
  for (int ch = tid; ch < CH * 3 * (FFp / 8); ch += 256) {   // 2016 chunks of 8
    int ci = ch / 63, rem = ch % 63;
    int rr = rem / 21, fc = rem % 21;
    int ts = t + rr - 1;
    float* dst = &ash[(ci * 3 + rr) * FFp + fc * 8];
    if (ts < 0 || ts >= TT) {
#pragma unroll
      for (int k2 = 0; k2 < 8; k2++) dst[k2] = 0.f;
    } else {
      s16x8 v = *(const s16x8*)(acts + ((size_t)(b * CH + ci) * TT + ts) * FFp + fc * 8);
#pragma unroll
      for (int k2 = 0; k2 < 8; k2++) dst[k2] = us2f((unsigned short)v[k2]);
    }
  }
  __syncthreads();
  int f = tid;
  if (f < OF) {
    float acc0 = bias[0], acc1 = bias[1];
#pragma unroll 4
    for (int ci = 0; ci < CH; ci++) {
      const float* row = &ash[ci * 3 * FFp];
      float xv[3][3];
#pragma unroll
      for (int kh = 0; kh < 3; kh++)
#pragma unroll
        for (int kw = 0; kw < 3; kw++) {
          int ff = f + kw - 1;
          xv[kh][kw] = (ff < 0) ? 0.f : row[kh * FFp + ff];   // ff==161 reads zero pad
        }
#pragma unroll
      for (int kh = 0; kh < 3; kh++)
#pragma unroll
        for (int kw = 0; kw < 3; kw++) {
          acc0 += xv[kh][kw] * w[((ci * 2 + 0) * 3 + (2 - kh)) * 3 + (2 - kw)];
          acc1 += xv[kh][kw] * w[((ci * 2 + 1) * 3 + (2 - kh)) * 3 + (2 - kw)];
        }
    }
    out[((size_t)(b * 2 + 0) * TT + t) * OF + f] = acc0;
    out[((size_t)(b * 2 + 1) * TT + t) * OF + f] = acc1;
  }
}

// ---------------- host launch ----------------
extern "C" void kernel_launch(void* const* d_in, const int* in_sizes, int n_in,
                              void* d_out, int out_size, void* d_ws, size_t ws_size,
                              hipStream_t stream) {
  const float* x            = (const float*)d_in[0];
  const float* conv_w       = (const float*)d_in[1];
  const float* conv_b       = (const float*)d_in[2];
  const float* gn_g         = (const float*)d_in[3];
  const float* gn_b         = (const float*)d_in[4];
  const float* intra_norm_g = (const float*)d_in[5];
  const float* intra_norm_b = (const float*)d_in[6];
  const float* intra_wih    = (const float*)d_in[7];
  const float* intra_whh    = (const float*)d_in[8];
  const float* intra_bih    = (const float*)d_in[9];
  const float* intra_bhh    = (const float*)d_in[10];
  const float* intra_lin_w  = (const float*)d_in[11];
  const float* intra_lin_b  = (const float*)d_in[12];
  const float* inter_norm_g = (const float*)d_in[13];
  const float* inter_norm_b = (const float*)d_in[14];
  const float* inter_wih    = (const float*)d_in[15];
  const float* inter_whh    = (const float*)d_in[16];
  const float* inter_bih    = (const float*)d_in[17];
  const float* inter_bhh    = (const float*)d_in[18];
  const float* inter_lin_w  = (const float*)d_in[19];
  const float* inter_lin_b  = (const float*)d_in[20];
  const float* q_w    = (const float*)d_in[21];
  const float* q_b    = (const float*)d_in[22];
  const float* q_a    = (const float*)d_in[23];
  const float* q_g    = (const float*)d_in[24];
  const float* q_beta = (const float*)d_in[25];
  const float* k_w    = (const float*)d_in[26];
  const float* k_b    = (const float*)d_in[27];
  const float* k_a    = (const float*)d_in[28];
  const float* k_g    = (const float*)d_in[29];
  const float* k_beta = (const float*)d_in[30];
  const float* v_w    = (const float*)d_in[31];
  const float* v_b    = (const float*)d_in[32];
  const float* v_a    = (const float*)d_in[33];
  const float* v_g    = (const float*)d_in[34];
  const float* v_beta = (const float*)d_in[35];
  const float* proj_w    = (const float*)d_in[36];
  const float* proj_b    = (const float*)d_in[37];
  const float* proj_a    = (const float*)d_in[38];
  const float* proj_g    = (const float*)d_in[39];
  const float* proj_beta = (const float*)d_in[40];
  const float* deconv_w  = (const float*)d_in[41];
  const float* deconv_b  = (const float*)d_in[42];

  // workspace: 256 B fp32 stats + bf16 arena of 129,153,024 elems = 246.3 MiB total.
  // Liveness-based aliasing:
  //   A act(21.676M)  B tmp(21.676M)  C hbuf(43.352M)  D res(21.676M)  E interc(20.773M)
  //   conv-out->E, qbuf->A, kbuf->B, vbuf->D, obuf->C (all dead at point of reuse)
  //   LSTM weight blobs overlay dead regions: intra blob -> D (dead until fold0),
  //   inter blob -> E (dead until fold1). Zero extra workspace.
  float* stats = (float*)d_ws;
  bf16* arena  = (bf16*)((char*)d_ws + 256);
  bf16* act    = arena;                  // A
  bf16* tmp    = arena + 21676032;       // B
  bf16* hbuf   = arena + 43352064;       // C
  bf16* res    = arena + 86704128;       // D
  bf16* interc = arena + 108380160;      // E  (end: 129,153,024)
  bf16* convout = interc;
  bf16* qbuf = act;
  bf16* kbuf = tmp;
  bf16* vbuf = res;
  bf16* obuf = hbuf;
  bf16* blob_intra = res;                // 2 x 524,288 bf16 = 2 MiB, dead until fold0
  bf16* blob_inter = interc;             // 524,288 bf16 = 1 MiB, dead until fold1

  hipMemsetAsync(stats, 0, 64 * sizeof(float), stream);
  conv_in_k<<<4032, 192, 0, stream>>>(x, conv_w, conv_b, convout);
  gn_reduce_k<<<512, 256, 0, stream>>>(convout, stats);
  gn_apply_k<<<84672, 256, 0, stream>>>(convout, stats, gn_g, gn_b, act);

  for (int l = 0; l < 4; l++) {
    lstm_prep_k<<<dim3(256, 2), 256, 0, stream>>>(
        intra_wih + (size_t)l * 524288, intra_whh + (size_t)l * 524288, blob_intra);
    ln_unfold_k<<<4032, 256, 0, stream>>>(act, intra_norm_g + l * 32, intra_norm_b + l * 32, tmp);
    lstm_mfma_k<<<dim3(126, 2), 512, 0, stream>>>(
        tmp, blob_intra, intra_bih + l * 2048, intra_bhh + l * 2048, hbuf, N1, LFi, 512, 1);
    fold_gemm_k<<<dim3(4, 1323), 256, 0, stream>>>(
        hbuf, intra_lin_w + (size_t)l * 131072, intra_lin_b + l * 32, act, res, 512, 0);
    lstm_prep_k<<<dim3(256, 1), 256, 0, stream>>>(
        inter_wih + (size_t)l * 262144, inter_whh + (size_t)l * 262144, blob_inter);
    ln_unfold8_k<<<dim3(LTi, BB), 256, 0, stream>>>(res, inter_norm_g + l * 32, inter_norm_b + l * 32, tmp);
    lstm_mfma_k<<<dim3(42, 1), 512, 0, stream>>>(
        tmp, blob_inter, inter_bih + l * 1024, inter_bhh + l * 1024, hbuf, N2, LTi, 256, 0);
    fold_gemm_k<<<dim3(4, 1323), 256, 0, stream>>>(
        hbuf, inter_lin_w + (size_t)l * 65536, inter_lin_b + l * 32, res, interc, 256, 1);
    qkv_k<<<dim3(4032, 4), 256, 0, stream>>>(interc,
        q_w + l * 512, q_b + l * 16, q_a + l * 4, q_g + l * 2576, q_beta + l * 2576,
        k_w + l * 512, k_b + l * 16, k_a + l * 4, k_g + l * 2576, k_beta + l * 2576,
        v_w + l * 1024, v_b + l * 32, v_a + l * 4, v_g + l * 5152, v_beta + l * 5152,
        qbuf, kbuf, vbuf);
    attn_k<<<dim3(504, 32), 256, 0, stream>>>(qbuf, kbuf, vbuf, obuf);
    proj_k<<<4032, 256, 0, stream>>>(obuf, proj_w + l * 1024, proj_b + l * 32, proj_a + l,
                                     proj_g + l * 5152, proj_beta + l * 5152, interc, act);
  }
  deconv_k<<<4032, 256, 0, stream>>>(act, deconv_w, deconv_b, (float*)d_out);
}

// Round 5
// 14709.631 us; speedup vs baseline: 1.2593x; 1.2593x over previous
//
#include <hip/hip_runtime.h>
#include <hip/hip_bf16.h>
#include <math.h>

// ---------------- problem constants ----------------
#define BB   8
#define CH   32
#define TT   504
#define FFp  168      // padded F
#define OF   161      // original F
#define KSZ  8
#define HID  256
#define NG   1024     // 4*H
#define NHh  4
#define EE   4
#define CVv  8
#define N1   4032     // B*T  (intra seqs)
#define N2   1344     // B*Fp (inter seqs)
#define LFi  21       // F/KS
#define LTi  63       // T/KS
#define EPSf 1e-5f

#define AS1 __attribute__((address_space(1)))
#define AS3 __attribute__((address_space(3)))

typedef __hip_bfloat16 bf16;
typedef __attribute__((ext_vector_type(8))) short s16x8;
typedef __attribute__((ext_vector_type(4))) float f32x4;

__device__ __forceinline__ float b2f(bf16 v) { return __bfloat162float(v); }
__device__ __forceinline__ bf16 f2b(float v) { return __float2bfloat16(v); }
__device__ __forceinline__ float us2f(unsigned short u) {
  return __uint_as_float(((unsigned)u) << 16);
}
__device__ __forceinline__ unsigned short f2bu(float v) {   // RNE bf16 bits
  unsigned u = __float_as_uint(v);
  unsigned r = u + 0x7fffu + ((u >> 16) & 1u);
  return (unsigned short)(r >> 16);
}
// unaligned 16-B bf16 vector load/store (rows start at odd elem offsets: OF=161)
__device__ __forceinline__ s16x8 ld8u(const short* p) {
  s16x8 v; __builtin_memcpy(&v, p, 16); return v;
}
__device__ __forceinline__ void st8u(short* p, const void* v) {
  __builtin_memcpy(p, v, 16);
}

__device__ __forceinline__ float sigm(float x) { return 1.f / (1.f + __expf(-x)); }
__device__ __forceinline__ float tanh_f(float x) {
  x = fminf(15.f, fmaxf(-15.f, x));
  float e = __expf(2.f * x);
  return (e - 1.f) / (e + 1.f);
}

// block = 256 threads (4 waves). red must be float[8] shared.
__device__ __forceinline__ void block_reduce2(float& s1, float& s2, float* red) {
#pragma unroll
  for (int off = 32; off > 0; off >>= 1) {
    s1 += __shfl_down(s1, off, 64);
    s2 += __shfl_down(s2, off, 64);
  }
  int lane = threadIdx.x & 63, wv = threadIdx.x >> 6;
  __syncthreads();
  if (lane == 0) { red[wv * 2] = s1; red[wv * 2 + 1] = s2; }
  __syncthreads();
  s1 = red[0] + red[2] + red[4] + red[6];
  s2 = red[1] + red[3] + red[5] + red[7];
}

// ---------------- K1: input conv 2->32, 3x3, pad 1 (LDS-tiled) ----------------
__global__ __launch_bounds__(192) void conv_in_k(const float* __restrict__ x,
                                                 const float* __restrict__ w,
                                                 const float* __restrict__ bias,
                                                 bf16* __restrict__ out) {
  __shared__ float xs[2 * 3 * (OF + 3)];
  int bt = blockIdx.x;
  int b = bt / TT, t = bt % TT;
  int tid = threadIdx.x;
  for (int i = tid; i < 2 * 3 * (OF + 3); i += 192) {
    int ci = i / (3 * (OF + 3));
    int rem = i % (3 * (OF + 3));
    int rr = rem / (OF + 3);
    int f = rem % (OF + 3);
    int ts = t + rr - 1;
    float v = 0.f;
    if (ts >= 0 && ts < TT && f < OF) v = x[((size_t)(b * 2 + ci) * TT + ts) * OF + f];
    xs[i] = v;
  }
  __syncthreads();
  int f = tid;
  if (f < OF) {
    float xv[2][3][3];
#pragma unroll
    for (int ci = 0; ci < 2; ci++)
#pragma unroll
      for (int kh = 0; kh < 3; kh++)
#pragma unroll
        for (int kw = 0; kw < 3; kw++) {
          int ff = f + kw - 1;
          xv[ci][kh][kw] = (ff < 0) ? 0.f : xs[(ci * 3 + kh) * (OF + 3) + ff];
        }
    for (int co = 0; co < CH; co++) {
      float acc = bias[co];
#pragma unroll
      for (int ci = 0; ci < 2; ci++)
#pragma unroll
        for (int kh = 0; kh < 3; kh++)
#pragma unroll
          for (int kw = 0; kw < 3; kw++)
            acc += xv[ci][kh][kw] * w[((co * 2 + ci) * 3 + kh) * 3 + kw];
      out[((size_t)(b * CH + co) * TT + t) * OF + f] = f2b(acc);
    }
  }
}

// ---------------- K2/K3: global per-batch norm ----------------
__global__ __launch_bounds__(256) void gn_reduce_k(const bf16* __restrict__ xin,
                                                   float* __restrict__ stats) {
  const int M = CH * TT * OF;   // 2,596,608
  int b = blockIdx.x >> 6;
  int part = blockIdx.x & 63;
  const bf16* p = xin + (size_t)b * M;
  float s1 = 0.f, s2 = 0.f;
  for (int i = part * 256 + threadIdx.x; i < M; i += 64 * 256) {
    float v = b2f(p[i]);
    s1 += v; s2 += v * v;
  }
  __shared__ float red[8];
  block_reduce2(s1, s2, red);
  if (threadIdx.x == 0) {
    atomicAdd(&stats[b * 2], s1);
    atomicAdd(&stats[b * 2 + 1], s2);
  }
}

__global__ __launch_bounds__(256) void gn_apply_k(const bf16* __restrict__ xin,
                                                  const float* __restrict__ stats,
                                                  const float* __restrict__ g,
                                                  const float* __restrict__ bb,
                                                  bf16* __restrict__ act) {
  int gid = blockIdx.x * 256 + threadIdx.x;       // B*CH*TT*FFp = 21,676,032 exact
  int f = gid % FFp;
  int t = (gid / FFp) % TT;
  int c = (gid / (FFp * TT)) % CH;
  int b = gid / (FFp * TT * CH);
  float v = 0.f;
  if (f < OF) {
    const float M = (float)(CH * TT * OF);
    float mu = stats[b * 2] / M;
    float var = stats[b * 2 + 1] / M - mu * mu;
    float xv = b2f(xin[((size_t)(b * CH + c) * TT + t) * OF + f]);
    v = (xv - mu) * rsqrtf(var + EPSf) * g[c] + bb[c];   // NOTE: no outer +eps here
  }
  act[gid] = f2b(v);
}

// ---------------- K4a: intra ln + unfold, vectorized staging (FFp-stride = aligned) ---
__global__ __launch_bounds__(256) void ln_unfold_k(const bf16* __restrict__ xin,
                                                   const float* __restrict__ g,
                                                   const float* __restrict__ bb,
                                                   bf16* __restrict__ out) {
  __shared__ float sm[CH * FFp];
  __shared__ float mu_s[FFp], rs_s[FFp];
  __shared__ float gg[CH], bv[CH];
  int bt = blockIdx.x;
  int b = bt / TT, t = bt % TT;
  int tid = threadIdx.x;
  if (tid < CH) { gg[tid] = g[tid]; bv[tid] = bb[tid]; }
  const short* base = (const short*)xin + ((size_t)b * CH * TT + t) * FFp;
  for (int idx = tid; idx < CH * LFi; idx += 256) {   // 672 aligned 16-B chunks
    int c = idx / LFi, ck = idx % LFi;
    int f0 = ck * 8;
    s16x8 v = *(const s16x8*)(base + (size_t)c * TT * FFp + f0);
#pragma unroll
    for (int k = 0; k < 8; k++) sm[c * FFp + f0 + k] = us2f((unsigned short)v[k]);
  }
  __syncthreads();
  if (tid < FFp) {
    int f = tid;
    float s1 = 0.f, s2 = 0.f;
#pragma unroll
    for (int c = 0; c < CH; c++) { float v = sm[c * FFp + f]; s1 += v; s2 += v * v; }
    float mu = s1 / CH;
    float var = s2 / CH - mu * mu;
    mu_s[f] = mu;
    rs_s[f] = 1.f / (sqrtf(var + EPSf) + EPSf);
  }
  __syncthreads();
  unsigned short* outu = (unsigned short*)out;
  for (int ch = tid; ch < LFi * CH; ch += 256) {     // 672 records
    int gI = ch >> 5, c = ch & 31;
    float gc = gg[c], bc = bv[c];
    unsigned short o8[8];
#pragma unroll
    for (int k = 0; k < 8; k++) {
      int f = gI * 8 + k;
      float v = (sm[c * FFp + f] - mu_s[f]) * rs_s[f] * gc + bc;
      o8[k] = f2bu(v);
    }
    *(uint4*)(outu + ((size_t)gI * N1 + bt) * 256 + c * 8) = *(uint4*)o8;
  }
}

// ---------------- K4b: inter ln + unfold, 8-t blocks, coalesced writes ----------------
__global__ __launch_bounds__(256) void ln_unfold8_k(const bf16* __restrict__ xin,
                                                    const float* __restrict__ g,
                                                    const float* __restrict__ bb,
                                                    bf16* __restrict__ out) {
  __shared__ short smb[8 * CH * FFp];              // 86016 B, [t8*32+c][f]
  __shared__ float mu_s[8 * FFp], rs_s[8 * FFp];   // 10752 B
  __shared__ float gg[CH], bv[CH];
  int tg = blockIdx.x, b = blockIdx.y;
  int tid = threadIdx.x;
  if (tid < CH) { gg[tid] = g[tid]; bv[tid] = bb[tid]; }
  const short* src = (const short*)xin;
  for (int idx = tid; idx < 8 * CH * (FFp / 8); idx += 256) {   // 5376 chunks of 8
    int t8 = idx / (CH * 21);
    int rem = idx % (CH * 21);
    int c = rem / 21, fc = rem % 21;
    s16x8 v = *(const s16x8*)(src + ((size_t)(b * CH + c) * TT + tg * 8 + t8) * FFp + fc * 8);
    *(s16x8*)(&smb[(t8 * CH + c) * FFp + fc * 8]) = v;
  }
  __syncthreads();
  for (int p = tid; p < 8 * FFp; p += 256) {       // 1344 (t8,f) pairs
    int t8 = p / FFp, f = p % FFp;
    float s1 = 0.f, s2 = 0.f;
#pragma unroll
    for (int c = 0; c < CH; c++) {
      float v = us2f((unsigned short)smb[(t8 * CH + c) * FFp + f]);
      s1 += v; s2 += v * v;
    }
    float mu = s1 / CH;
    float var = s2 / CH - mu * mu;
    mu_s[p] = mu;
    rs_s[p] = 1.f / (sqrtf(var + EPSf) + EPSf);
  }
  __syncthreads();
  unsigned short* outu = (unsigned short*)out;
  for (int ch = tid; ch < FFp * CH; ch += 256) {   // 5376 records
    int f = ch >> 5, c = ch & 31;
    float gc = gg[c], bc = bv[c];
    unsigned short o8[8];
#pragma unroll
    for (int k = 0; k < 8; k++) {
      float v = us2f((unsigned short)smb[(k * CH + c) * FFp + f]);
      v = (v - mu_s[k * FFp + f]) * rs_s[k * FFp + f] * gc + bc;
      o8[k] = f2bu(v);
    }
    *(uint4*)(outu + ((size_t)tg * N2 + b * FFp + f) * 256 + c * 8) = *(uint4*)o8;
  }
}

// ---------------- K5a: weight prep — reorder W=[wih|whh] into B-fragment blob ---------
__global__ __launch_bounds__(256) void lstm_prep_k(const float* __restrict__ wih0,
                                                   const float* __restrict__ whh0,
                                                   bf16* __restrict__ blob0) {
  int dir = blockIdx.y;
  const float* wih = wih0 + (size_t)dir * 262144;
  const float* whh = whh0 + (size_t)dir * 262144;
  unsigned short* blob = (unsigned short*)(blob0 + (size_t)dir * 524288);
  int gid = blockIdx.x * 256 + threadIdx.x;     // 0..65535
  int lane = gid & 63;
  int ks = (gid >> 6) & 15;
  int nt = gid >> 10;
  int n = nt * 16 + (lane & 15);
  int kb = ks * 32 + (lane >> 4) * 8;
  unsigned short o8[8];
#pragma unroll
  for (int j = 0; j < 8; j++) {
    int k = kb + j;
    float v = (k < 256) ? wih[n * 256 + k] : whh[n * 256 + (k - 256)];
    o8[j] = f2bu(v);
  }
  *(uint4*)(blob + (size_t)gid * 8) = *(uint4*)o8;
}

// ---------------- K5b: MFMA LSTM — EXACT R3 version (benched 15127 us) ----------------
// R14 post-mortem: R4's register-staged B regressed (steady 1.70->2.30 ms, FETCH
// 36MB->1.15GB: blob fell out of L2; also LDS drop allowed 2 blocks/CU). Four rounds
// of evidence: per-BLOCK weight-stream time ~81-92 us/step for 1 MiB is invariant
// across M (16/32), phase rotation, pipeline depth, and load path. This revision
// reverts to the proven R3 kernel verbatim; the round's optimization budget goes to
// the scalar-load kernels (attn/qkv/proj/ln_unfold).
template<int PH>
__device__ __forceinline__ void lstm_run(short* __restrict__ afr,
                                         short* __restrict__ bst_w,
                                         const short* __restrict__ xzs,
                                         const short* __restrict__ blob,
                                         const float* __restrict__ bih,
                                         const float* __restrict__ bhh,
                                         unsigned short* __restrict__ houtu,
                                         int N, int Ls, int hstride, int hoff,
                                         int n0, int dirrev, int w, int lane) {
  int tid = w * 64 + lane;
  int l15 = lane & 15, lq = lane >> 4;

  float bias[4][2];
#pragma unroll
  for (int q = 0; q < 4; q++)
#pragma unroll
    for (int j = 0; j < 2; j++) {
      int n = q * 256 + (2 * w + j) * 16 + l15;
      bias[q][j] = bih[n] + bhh[n];
    }
  for (int i = tid; i < 8192; i += 512) afr[8192 + i] = 0;   // h frags = 0
  float cst[16];
#pragma unroll
  for (int i = 0; i < 16; i++) cst[i] = 0.f;

#define BQ_ISSUE(P)                                                              \
  {                                                                              \
    const int a_ = (((P) >> 4) + PH) & 3;                                        \
    const int r_ = ((P) >> 1) & 7, h2_ = (P) & 1;                                \
    const int nt_ = (r_ >> 1) * 16 + 2 * w + (r_ & 1);                           \
    const short* gb_ = blob + (size_t)nt_ * 8192 + (a_ * 4 + h2_ * 2) * 512 + lane * 8; \
    short* lb_ = bst_w + ((P) % 6) * 1024;                                       \
    _Pragma("unroll")                                                            \
    for (int k_ = 0; k_ < 2; k_++)                                               \
      __builtin_amdgcn_global_load_lds((const AS1 void*)(gb_ + k_ * 512),        \
                                       (AS3 void*)(lb_ + k_ * 512), 16, 0, 0);   \
  }

  for (int st = 0; st < Ls; st++) {
    int t = dirrev ? (Ls - 1 - st) : st;
    {
      const short* gx = xzs + ((size_t)t * N + n0 + l15) * 256 + (w * 4 + lq) * 8;
      __builtin_amdgcn_global_load_lds((const AS1 void*)gx,
                                       (AS3 void*)(afr + (w * 2 + 0) * 512), 16, 0, 2);
      __builtin_amdgcn_global_load_lds((const AS1 void*)(gx + 16 * 256),
                                       (AS3 void*)(afr + (w * 2 + 1) * 512), 16, 0, 2);
    }
    BQ_ISSUE(0);
    BQ_ISSUE(1);
    BQ_ISSUE(2);
    BQ_ISSUE(3);
    BQ_ISSUE(4);
    __syncthreads();   // BARRIER-A: drains all DMA (x + positions 0..4), h visible

    f32x4 acc[2][4][2];
#pragma unroll
    for (int mt = 0; mt < 2; mt++)
#pragma unroll
      for (int q = 0; q < 4; q++)
#pragma unroll
        for (int j = 0; j < 2; j++)
          acc[mt][q][j] = (f32x4){bias[q][j], bias[q][j], bias[q][j], bias[q][j]};

    s16x8 af[4][2];
#pragma unroll
    for (int C = 0; C < 64; C++) {
      const int s = C >> 1, h2 = C & 1;
      const int rR = s & 7;
      const int q = rR >> 1, j = rR & 1;     // static acc index
      if (rR == 0 && h2 == 0) {
        const int a = ((s >> 3) + PH) & 3;   // compile-time under template
#pragma unroll
        for (int k = 0; k < 4; k++)
#pragma unroll
          for (int mt = 0; mt < 2; mt++)
            af[k][mt] = *(const s16x8*)(&afr[(((a * 4 + k) * 2 + mt) * 64 + lane) * 8]);
      }
      // sound waits: chunk C resident iff allowed-outstanding = 2*(min(C+4,63)-C)
      if (C <= 59)      __builtin_amdgcn_s_waitcnt(0x0F78);   // vmcnt(8)
      else if (C == 60) __builtin_amdgcn_s_waitcnt(0x0F76);   // vmcnt(6)
      else if (C == 61) __builtin_amdgcn_s_waitcnt(0x0F74);   // vmcnt(4)
      else if (C == 62) __builtin_amdgcn_s_waitcnt(0x0F72);   // vmcnt(2)
      else              __builtin_amdgcn_s_waitcnt(0x0F70);   // vmcnt(0)
      const short* lb = bst_w + (C % 6) * 1024;
#pragma unroll
      for (int k = 0; k < 2; k++) {
        s16x8 bf = *(const s16x8*)(lb + k * 512 + lane * 8);
        acc[0][q][j] = __builtin_amdgcn_mfma_f32_16x16x32_bf16(af[h2 * 2 + k][0], bf, acc[0][q][j], 0, 0, 0);
        acc[1][q][j] = __builtin_amdgcn_mfma_f32_16x16x32_bf16(af[h2 * 2 + k][1], bf, acc[1][q][j], 0, 0, 0);
      }
      if (C < 59) BQ_ISSUE(C + 5);
    }
    __syncthreads();   // BARRIER-B: all afr reads done before h overwrite

#pragma unroll
    for (int mt = 0; mt < 2; mt++)
#pragma unroll
      for (int j = 0; j < 2; j++) {
        int d = (2 * w + j) * 16 + l15;
        int slotb = ((8 + (d >> 5)) * 2 + mt) * 64 + ((d >> 3) & 3) * 16;
#pragma unroll
        for (int r = 0; r < 4; r++) {
          int m = lq * 4 + r;
          float iv = sigm(acc[mt][0][j][r]);
          float fv = sigm(acc[mt][1][j][r]);
          float gv = tanh_f(acc[mt][2][j][r]);
          float ov = sigm(acc[mt][3][j][r]);
          float c = fv * cst[mt * 8 + j * 4 + r] + iv * gv;
          cst[mt * 8 + j * 4 + r] = c;
          float h = ov * tanh_f(c);
          unsigned short hb = f2bu(h);
          houtu[((size_t)t * N + n0 + mt * 16 + m) * hstride + hoff + d] = hb;
          afr[(slotb + m) * 8 + (d & 7)] = (short)hb;
        }
      }
  }
#undef BQ_ISSUE
}

__global__ __launch_bounds__(512) void lstm_mfma_k(const bf16* __restrict__ xz,
                                                   const bf16* __restrict__ blob0,
                                                   const float* __restrict__ bih0,
                                                   const float* __restrict__ bhh0,
                                                   bf16* __restrict__ hout,
                                                   int N, int Ls, int hstride, int bidir) {
  __shared__ __attribute__((aligned(16))) short afr[16 * 2 * 64 * 8];   // 32 KiB
  __shared__ __attribute__((aligned(16))) short bstage[8 * 6 * 1024];   // 96 KiB static
  int tid = threadIdx.x;
  int w = tid >> 6, lane = tid & 63;
  int dir = blockIdx.y;
  const short* blob = (const short*)(blob0 + (size_t)dir * 524288);
  const float* bih = bih0 + dir * NG;
  const float* bhh = bhh0 + dir * NG;
  int hoff = dir * 256;
  int n0 = blockIdx.x * 32;
  int dirrev = (bidir && dir) ? 1 : 0;
  unsigned short* houtu = (unsigned short*)hout;
  const short* xzs = (const short*)xz;
  short* bst_w = bstage + w * 6144;      // per-wave 12 KiB: 6 bufs x 2 frags x 512 shorts
  int PH = ((blockIdx.x >> 3) + blockIdx.x) & 3;
  switch (PH) {
    case 0: lstm_run<0>(afr, bst_w, xzs, blob, bih, bhh, houtu, N, Ls, hstride, hoff, n0, dirrev, w, lane); break;
    case 1: lstm_run<1>(afr, bst_w, xzs, blob, bih, bhh, houtu, N, Ls, hstride, hoff, n0, dirrev, w, lane); break;
    case 2: lstm_run<2>(afr, bst_w, xzs, blob, bih, bhh, houtu, N, Ls, hstride, hoff, n0, dirrev, w, lane); break;
    default: lstm_run<3>(afr, bst_w, xzs, blob, bih, bhh, houtu, N, Ls, hstride, hoff, n0, dirrev, w, lane); break;
  }
}

// ---------------- K6: fold GEMM (M=84672, N=256) + bias + residual, scatter epilogue ---
__global__ __launch_bounds__(256) void fold_gemm_k(const bf16* __restrict__ A,
                                                   const float* __restrict__ Bw,
                                                   const float* __restrict__ linb,
                                                   const bf16* __restrict__ resid,
                                                   bf16* __restrict__ outp,
                                                   int K, int mode) {
  __shared__ float As[16 * 68];
  __shared__ float Bs[16 * 64];
  int tid = threadIdx.x;
  int n0 = blockIdx.x * 64;
  int m0 = blockIdx.y * 64;
  int tr = tid >> 4, tc = tid & 15;
  float acc[4][4] = {};
  int arow = tid >> 2, akg = (tid & 3) * 4;
  int bkk = tid >> 4, bc4 = (tid & 15) * 4;
  for (int k0 = 0; k0 < K; k0 += 16) {
    ushort4 avu = *(const ushort4*)((const unsigned short*)A + (size_t)(m0 + arow) * K + k0 + akg);
    float4 bv = *(const float4*)(Bw + (size_t)(k0 + bkk) * 256 + n0 + bc4);
    __syncthreads();
    As[(akg + 0) * 68 + arow] = us2f(avu.x);
    As[(akg + 1) * 68 + arow] = us2f(avu.y);
    As[(akg + 2) * 68 + arow] = us2f(avu.z);
    As[(akg + 3) * 68 + arow] = us2f(avu.w);
    *(float4*)(&Bs[bkk * 64 + bc4]) = bv;
    __syncthreads();
#pragma unroll
    for (int kk = 0; kk < 16; kk++) {
      float4 a4 = *(const float4*)(&As[kk * 68 + tr * 4]);
      float4 b4 = *(const float4*)(&Bs[kk * 64 + tc * 4]);
      float aa[4] = {a4.x, a4.y, a4.z, a4.w};
      float bb_[4] = {b4.x, b4.y, b4.z, b4.w};
#pragma unroll
      for (int i = 0; i < 4; i++)
#pragma unroll
        for (int j = 0; j < 4; j++) acc[i][j] += aa[i] * bb_[j];
    }
  }
#pragma unroll
  for (int i = 0; i < 4; i++) {
    int r = m0 + tr * 4 + i;
#pragma unroll
    for (int j = 0; j < 4; j++) {
      int col = n0 + tc * 4 + j;
      int c = col >> 3, kp = col & 7;
      float v = acc[i][j] + linb[c];
      if (mode == 0) {
        int l = r / N1, n = r % N1;
        int b = n / TT, t = n % TT;
        size_t o = ((size_t)(b * CH + c) * TT + t) * FFp + (l * 8 + kp);
        outp[o] = f2b(v + b2f(resid[o]));
      } else {
        int l = r / N2, n = r % N2;
        int b = n / FFp, fq = n % FFp;
        int t = l * 8 + kp;
        if (fq < OF) {
          size_t o = ((size_t)(b * CH + c) * TT + t) * OF + fq;
          size_t ri = ((size_t)(b * CH + c) * TT + t) * FFp + fq;
          outp[o] = f2b(v + b2f(resid[ri]));
        }
      }
    }
  }
}

// ---------------- K8: fused QKV projection + prelu + ln_cf_head (vec staging) ---------
__global__ __launch_bounds__(256) void qkv_k(const bf16* __restrict__ interc,
    const float* __restrict__ qw, const float* __restrict__ qb, const float* __restrict__ qa,
    const float* __restrict__ qg, const float* __restrict__ qbeta,
    const float* __restrict__ kw, const float* __restrict__ kb, const float* __restrict__ ka,
    const float* __restrict__ kg, const float* __restrict__ kbeta,
    const float* __restrict__ vw, const float* __restrict__ vb, const float* __restrict__ va,
    const float* __restrict__ vg, const float* __restrict__ vbeta,
    bf16* __restrict__ qo, bf16* __restrict__ ko, bf16* __restrict__ vo) {
  __shared__ float sm[CH * OF];     // 5152
  __shared__ float wb[16 * 32];
  __shared__ float wbias[16];
  __shared__ float yb[16 * OF];     // 2576: [0:4) Q-e, [4:8) K-e, [8:16) V-cv
  __shared__ float red[8];
  int bt = blockIdx.x, h = blockIdx.y;
  int b = bt / TT, t = bt % TT;
  int tid = threadIdx.x;
  const short* src = (const short*)interc + ((size_t)b * CH * TT + t) * OF;
  for (int idx = tid; idx < CH * 21; idx += 256) {   // 672 chunk items
    int c = idx / 21, ck = idx % 21;
    if (ck < 20) {
      int f0 = ck * 8;
      s16x8 v = ld8u(src + (size_t)c * TT * OF + f0);
#pragma unroll
      for (int k = 0; k < 8; k++) sm[c * OF + f0 + k] = us2f((unsigned short)v[k]);
    } else {
      sm[c * OF + 160] = us2f((unsigned short)src[(size_t)c * TT * OF + 160]);
    }
  }
  for (int idx = tid; idx < 512; idx += 256) {
    int e = idx >> 5, c = idx & 31;
    float w;
    if (e < 4) w = qw[(h * 4 + e) * 32 + c];
    else if (e < 8) w = kw[(h * 4 + e - 4) * 32 + c];
    else w = vw[(h * 8 + e - 8) * 32 + c];
    wb[idx] = w;
  }
  if (tid < 16) {
    float bv;
    if (tid < 4) bv = qb[h * 4 + tid];
    else if (tid < 8) bv = kb[h * 4 + tid - 4];
    else bv = vb[h * 8 + tid - 8];
    wbias[tid] = bv;
  }
  __syncthreads();
  float aQ = qa[h], aK = ka[h], aV = va[h];
  for (int idx = tid; idx < 16 * OF; idx += 256) {
    int e = idx / OF, f = idx % OF;
    float accv = wbias[e];
#pragma unroll
    for (int c = 0; c < 32; c++) accv += sm[c * OF + f] * wb[e * 32 + c];
    float a = e < 4 ? aQ : (e < 8 ? aK : aV);
    yb[idx] = accv >= 0.f ? accv : a * accv;
  }
  __syncthreads();
  for (int seg = 0; seg < 3; seg++) {
    int s0 = (seg == 0) ? 0 : ((seg == 1) ? 644 : 1288);
    int len = (seg == 2) ? 1288 : 644;
    float s1 = 0.f, s2 = 0.f;
    for (int i = tid; i < len; i += 256) { float v = yb[s0 + i]; s1 += v; s2 += v * v; }
    block_reduce2(s1, s2, red);
    float mu = s1 / len;
    float var = s2 / len - mu * mu;
    float rs = 1.f / (sqrtf(var + EPSf) + EPSf);
    const float* gp; const float* bp; bf16* op; int nch;
    if (seg == 0) { gp = qg; bp = qbeta; op = qo; nch = 4; }
    else if (seg == 1) { gp = kg; bp = kbeta; op = ko; nch = 4; }
    else { gp = vg; bp = vbeta; op = vo; nch = 8; }
    for (int i = tid; i < len; i += 256) {
      int e = i / OF, f = i % OF;
      float v = (yb[s0 + i] - mu) * rs * gp[(h * nch + e) * OF + f] + bp[(h * nch + e) * OF + f];
      op[(((size_t)(h * BB + b) * nch + e) * TT + t) * OF + f] = f2b(v);
    }
  }
}

// ---------------- K9: banded causal attention (lookback 5), vectorized loads ----------
__global__ __launch_bounds__(256) void attn_k(const bf16* __restrict__ Q,
                                              const bf16* __restrict__ Kt,
                                              const bf16* __restrict__ V,
                                              bf16* __restrict__ O) {
  int t = blockIdx.x;
  int hb = blockIdx.y;            // h*8 + b
  int h = hb >> 3, b = hb & 7;
  int tid = threadIdx.x;
  int nv = min(t, 5) + 1;
  const float scale = 0.0394055201f;   // 1/sqrt(644)
  __shared__ float redl[24];
  float part[6] = {0, 0, 0, 0, 0, 0};
  size_t qkbase = ((size_t)(h * BB + b) * EE) * TT * OF;
  const short* Qs = (const short*)Q;
  const short* Ks = (const short*)Kt;
  // phase 1: QK^T band. 84 chunk items: (e in [0,4)) x (ck in [0,21))
  if (tid < EE * 21) {
    int e = tid / 21, ck = tid % 21;
    size_t rbase = qkbase + (size_t)e * TT * OF;
    if (ck < 20) {
      int f0 = ck * 8;
      s16x8 qv = ld8u(Qs + rbase + (size_t)t * OF + f0);
      float qf[8];
#pragma unroll
      for (int k = 0; k < 8; k++) qf[k] = us2f((unsigned short)qv[k]);
#pragma unroll
      for (int d = 0; d < 6; d++)
        if (d < nv) {
          s16x8 kv = ld8u(Ks + rbase + (size_t)(t - d) * OF + f0);
          float s = 0.f;
#pragma unroll
          for (int k = 0; k < 8; k++) s += qf[k] * us2f((unsigned short)kv[k]);
          part[d] += s;
        }
    } else {   // tail f=160, scalar (no overread)
      float qf = us2f((unsigned short)Qs[rbase + (size_t)t * OF + 160]);
#pragma unroll
      for (int d = 0; d < 6; d++)
        if (d < nv) part[d] += qf * us2f((unsigned short)Ks[rbase + (size_t)(t - d) * OF + 160]);
    }
  }
#pragma unroll
  for (int d = 0; d < 6; d++)
#pragma unroll
    for (int off = 32; off > 0; off >>= 1) part[d] += __shfl_down(part[d], off, 64);
  int lane = tid & 63, wv = tid >> 6;
  if (lane == 0) {
#pragma unroll
    for (int d = 0; d < 6; d++) redl[wv * 6 + d] = part[d];
  }
  __syncthreads();
  float a[6], sv[6];
  float m = -1e30f;
#pragma unroll
  for (int d = 0; d < 6; d++)
    if (d < nv) {
      float s = (redl[d] + redl[6 + d] + redl[12 + d] + redl[18 + d]) * scale;
      sv[d] = s;
      m = fmaxf(m, s);
    }
  float denom = 0.f;
#pragma unroll
  for (int d = 0; d < 6; d++)
    if (d < nv) { a[d] = __expf(sv[d] - m); denom += a[d]; }
  float inv = 1.f / denom;
  // phase 2: PV. 168 chunk items: (cv in [0,8)) x (ck in [0,21))
  size_t vbase = ((size_t)(h * BB + b) * CVv) * TT * OF;
  const short* Vs = (const short*)V;
  short* Os = (short*)O;
  if (tid < CVv * 21) {
    int cv = tid / 21, ck = tid % 21;
    size_t rbase = vbase + (size_t)cv * TT * OF;
    size_t obase = (((size_t)b * CH + h * CVv + cv) * TT + t) * OF;
    if (ck < 20) {
      int f0 = ck * 8;
      float o[8] = {0, 0, 0, 0, 0, 0, 0, 0};
#pragma unroll
      for (int d = 0; d < 6; d++)
        if (d < nv) {
          s16x8 vv = ld8u(Vs + rbase + (size_t)(t - d) * OF + f0);
#pragma unroll
          for (int k = 0; k < 8; k++) o[k] += a[d] * us2f((unsigned short)vv[k]);
        }
      unsigned short o8[8];
#pragma unroll
      for (int k = 0; k < 8; k++) o8[k] = f2bu(o[k] * inv);
      st8u(Os + obase + f0, o8);
    } else {   // tail f=160, scalar
      float o = 0.f;
#pragma unroll
      for (int d = 0; d < 6; d++)
        if (d < nv) o += a[d] * us2f((unsigned short)Vs[rbase + (size_t)(t - d) * OF + 160]);
      Os[obase + 160] = (short)f2bu(o * inv);
    }
  }
}

// ---------------- K10: proj + prelu + ln_cf_proj + residual + re-pad (vec staging) ----
__global__ __launch_bounds__(256) void proj_k(const bf16* __restrict__ ob,
                                              const float* __restrict__ pw,
                                              const float* __restrict__ pb,
                                              const float* __restrict__ pa,
                                              const float* __restrict__ pg,
                                              const float* __restrict__ pbeta,
                                              const bf16* __restrict__ interc,
                                              bf16* __restrict__ act) {
  __shared__ float sm[CH * OF];
  __shared__ float wsm[CH * CH];
  __shared__ float yb[CH * OF];
  __shared__ float red[8];
  int bt = blockIdx.x;
  int b = bt / TT, t = bt % TT;
  int tid = threadIdx.x;
  const short* src = (const short*)ob + ((size_t)b * CH * TT + t) * OF;
  for (int idx = tid; idx < CH * 21; idx += 256) {   // 672 chunk items
    int c = idx / 21, ck = idx % 21;
    if (ck < 20) {
      int f0 = ck * 8;
      s16x8 v = ld8u(src + (size_t)c * TT * OF + f0);
#pragma unroll
      for (int k = 0; k < 8; k++) sm[c * OF + f0 + k] = us2f((unsigned short)v[k]);
    } else {
      sm[c * OF + 160] = us2f((unsigned short)src[(size_t)c * TT * OF + 160]);
    }
  }
  for (int idx = tid; idx < CH * CH; idx += 256) wsm[idx] = pw[idx];
  __syncthreads();
  float aP = pa[0];
  for (int idx = tid; idx < CH * OF; idx += 256) {
    int d = idx / OF, f = idx % OF;
    float accv = pb[d];
#pragma unroll
    for (int c = 0; c < 32; c++) accv += sm[c * OF + f] * wsm[d * 32 + c];
    yb[idx] = accv >= 0.f ? accv : aP * accv;
  }
  __syncthreads();
  float s1 = 0.f, s2 = 0.f;
  for (int i = tid; i < CH * OF; i += 256) { float v = yb[i]; s1 += v; s2 += v * v; }
  block_reduce2(s1, s2, red);
  const float Mn = (float)(CH * OF);
  float mu = s1 / Mn;
  float var = s2 / Mn - mu * mu;
  float rs = 1.f / (sqrtf(var + EPSf) + EPSf);
  for (int idx = tid; idx < CH * FFp; idx += 256) {
    int d = idx / FFp, f = idx % FFp;
    float v = 0.f;
    if (f < OF) {
      float y = (yb[d * OF + f] - mu) * rs * pg[d * OF + f] + pbeta[d * OF + f];
      v = y + b2f(interc[((size_t)(b * CH + d) * TT + t) * OF + f]);
    }
    act[((size_t)(b * CH + d) * TT + t) * FFp + f] = f2b(v);
  }
}

// ---------------- K11: output deconv (LDS-tiled 3x3 conv over 32ch) -------------------
// NOTE: grid MUST be exactly B*TT = 4032 (block-per-(b,t)); larger grids write OOB.
__global__ __launch_bounds__(256) void deconv_k(const bf16* __restrict__ act,
                                                const float* __restrict__ w,
                                                const float* __restrict__ bias,
                                                float* __restrict__ out) {
  __shared__ float ash[CH * 3 * FFp];   // 64512 B
  int bt = blockIdx.x;
  int b = bt / TT, t = bt % TT;
  int tid = threadIdx.x;
  const short* acts = (const short*)act;
  for (int ch = tid; ch < CH * 3 * (FFp / 8); ch += 256) {   // 2016 chunks of 8
    int ci = ch / 63, rem = ch % 63;
    int rr = rem / 21, fc = rem % 21;
    int ts = t + rr - 1;
    float* dst = &ash[(ci * 3 + rr) * FFp + fc * 8];
    if (ts < 0 || ts >= TT) {
#pragma unroll
      for (int k2 = 0; k2 < 8; k2++) dst[k2] = 0.f;
    } else {
      s16x8 v = *(const s16x8*)(acts + ((size_t)(b * CH + ci) * TT + ts) * FFp + fc * 8);
#pragma unroll
      for (int k2 = 0; k2 < 8; k2++) dst[k2] = us2f((unsigned short)v[k2]);
    }
  }
  __syncthreads();
  int f = tid;
  if (f < OF) {
    float acc0 = bias[0], acc1 = bias[1];
#pragma unroll 4
    for (int ci = 0; ci < CH; ci++) {
      const float* row = &ash[ci * 3 * FFp];
      float xv[3][3];
#pragma unroll
      for (int kh = 0; kh < 3; kh++)
#pragma unroll
        for (int kw = 0; kw < 3; kw++) {
          int ff = f + kw - 1;
          xv[kh][kw] = (ff < 0) ? 0.f : row[kh * FFp + ff];   // ff==161 reads zero pad
        }
#pragma unroll
      for (int kh = 0; kh < 3; kh++)
#pragma unroll
        for (int kw = 0; kw < 3; kw++) {
          acc0 += xv[kh][kw] * w[((ci * 2 + 0) * 3 + (2 - kh)) * 3 + (2 - kw)];
          acc1 += xv[kh][kw] * w[((ci * 2 + 1) * 3 + (2 - kh)) * 3 + (2 - kw)];
        }
    }
    out[((size_t)(b * 2 + 0) * TT + t) * OF + f] = acc0;
    out[((size_t)(b * 2 + 1) * TT + t) * OF + f] = acc1;
  }
}

// ---------------- host launch ----------------
extern "C" void kernel_launch(void* const* d_in, const int* in_sizes, int n_in,
                              void* d_out, int out_size, void* d_ws, size_t ws_size,
                              hipStream_t stream) {
  const float* x            = (const float*)d_in[0];
  const float* conv_w       = (const float*)d_in[1];
  const float* conv_b       = (const float*)d_in[2];
  const float* gn_g         = (const float*)d_in[3];
  const float* gn_b         = (const float*)d_in[4];
  const float* intra_norm_g = (const float*)d_in[5];
  const float* intra_norm_b = (const float*)d_in[6];
  const float* intra_wih    = (const float*)d_in[7];
  const float* intra_whh    = (const float*)d_in[8];
  const float* intra_bih    = (const float*)d_in[9];
  const float* intra_bhh    = (const float*)d_in[10];
  const float* intra_lin_w  = (const float*)d_in[11];
  const float* intra_lin_b  = (const float*)d_in[12];
  const float* inter_norm_g = (const float*)d_in[13];
  const float* inter_norm_b = (const float*)d_in[14];
  const float* inter_wih    = (const float*)d_in[15];
  const float* inter_whh    = (const float*)d_in[16];
  const float* inter_bih    = (const float*)d_in[17];
  const float* inter_bhh    = (const float*)d_in[18];
  const float* inter_lin_w  = (const float*)d_in[19];
  const float* inter_lin_b  = (const float*)d_in[20];
  const float* q_w    = (const float*)d_in[21];
  const float* q_b    = (const float*)d_in[22];
  const float* q_a    = (const float*)d_in[23];
  const float* q_g    = (const float*)d_in[24];
  const float* q_beta = (const float*)d_in[25];
  const float* k_w    = (const float*)d_in[26];
  const float* k_b    = (const float*)d_in[27];
  const float* k_a    = (const float*)d_in[28];
  const float* k_g    = (const float*)d_in[29];
  const float* k_beta = (const float*)d_in[30];
  const float* v_w    = (const float*)d_in[31];
  const float* v_b    = (const float*)d_in[32];
  const float* v_a    = (const float*)d_in[33];
  const float* v_g    = (const float*)d_in[34];
  const float* v_beta = (const float*)d_in[35];
  const float* proj_w    = (const float*)d_in[36];
  const float* proj_b    = (const float*)d_in[37];
  const float* proj_a    = (const float*)d_in[38];
  const float* proj_g    = (const float*)d_in[39];
  const float* proj_beta = (const float*)d_in[40];
  const float* deconv_w  = (const float*)d_in[41];
  const float* deconv_b  = (const float*)d_in[42];

  // workspace: 256 B fp32 stats + bf16 arena of 129,153,024 elems = 246.3 MiB total.
  float* stats = (float*)d_ws;
  bf16* arena  = (bf16*)((char*)d_ws + 256);
  bf16* act    = arena;                  // A
  bf16* tmp    = arena + 21676032;       // B
  bf16* hbuf   = arena + 43352064;       // C
  bf16* res    = arena + 86704128;       // D
  bf16* interc = arena + 108380160;      // E  (end: 129,153,024)
  bf16* convout = interc;
  bf16* qbuf = act;
  bf16* kbuf = tmp;
  bf16* vbuf = res;
  bf16* obuf = hbuf;
  bf16* blob_intra = res;                // 2 x 524,288 bf16 = 2 MiB, dead until fold0
  bf16* blob_inter = interc;             // 524,288 bf16 = 1 MiB, dead until fold1

  hipMemsetAsync(stats, 0, 64 * sizeof(float), stream);
  conv_in_k<<<4032, 192, 0, stream>>>(x, conv_w, conv_b, convout);
  gn_reduce_k<<<512, 256, 0, stream>>>(convout, stats);
  gn_apply_k<<<84672, 256, 0, stream>>>(convout, stats, gn_g, gn_b, act);

  for (int l = 0; l < 4; l++) {
    lstm_prep_k<<<dim3(256, 2), 256, 0, stream>>>(
        intra_wih + (size_t)l * 524288, intra_whh + (size_t)l * 524288, blob_intra);
    ln_unfold_k<<<4032, 256, 0, stream>>>(act, intra_norm_g + l * 32, intra_norm_b + l * 32, tmp);
    lstm_mfma_k<<<dim3(126, 2), 512, 0, stream>>>(
        tmp, blob_intra, intra_bih + l * 2048, intra_bhh + l * 2048, hbuf, N1, LFi, 512, 1);
    fold_gemm_k<<<dim3(4, 1323), 256, 0, stream>>>(
        hbuf, intra_lin_w + (size_t)l * 131072, intra_lin_b + l * 32, act, res, 512, 0);
    lstm_prep_k<<<dim3(256, 1), 256, 0, stream>>>(
        inter_wih + (size_t)l * 262144, inter_whh + (size_t)l * 262144, blob_inter);
    ln_unfold8_k<<<dim3(LTi, BB), 256, 0, stream>>>(res, inter_norm_g + l * 32, inter_norm_b + l * 32, tmp);
    lstm_mfma_k<<<dim3(42, 1), 512, 0, stream>>>(
        tmp, blob_inter, inter_bih + l * 1024, inter_bhh + l * 1024, hbuf, N2, LTi, 256, 0);
    fold_gemm_k<<<dim3(4, 1323), 256, 0, stream>>>(
        hbuf, inter_lin_w + (size_t)l * 65536, inter_lin_b + l * 32, res, interc, 256, 1);
    qkv_k<<<dim3(4032, 4), 256, 0, stream>>>(interc,
        q_w + l * 512, q_b + l * 16, q_a + l * 4, q_g + l * 2576, q_beta + l * 2576,
        k_w + l * 512, k_b + l * 16, k_a + l * 4, k_g + l * 2576, k_beta + l * 2576,
        v_w + l * 1024, v_b + l * 32, v_a + l * 4, v_g + l * 5152, v_beta + l * 5152,
        qbuf, kbuf, vbuf);
    attn_k<<<dim3(504, 32), 256, 0, stream>>>(qbuf, kbuf, vbuf, obuf);
    proj_k<<<4032, 256, 0, stream>>>(obuf, proj_w + l * 1024, proj_b + l * 32, proj_a + l,
                                     proj_g + l * 5152, proj_beta + l * 5152, interc, act);
  }
  deconv_k<<<4032, 256, 0, stream>>>(act, deconv_w, deconv_b, (float*)d_out);
}